// Round 5
// baseline (2109.732 us; speedup 1.0000x reference)
//
#include <hip/hip_runtime.h>
#include <hip/hip_bf16.h>

#define BATCH 4096
#define KD    2048
#define HD    2048

typedef float f32x4 __attribute__((ext_vector_type(4)));
typedef short bf16x8 __attribute__((ext_vector_type(8)));

__device__ __forceinline__ unsigned short f2bf(float f) {
  unsigned int u = __builtin_bit_cast(unsigned int, f);
  u = (u + 0x7fffu + ((u >> 16) & 1u)) >> 16;   // RNE (inputs bounded, no NaN)
  return (unsigned short)u;
}

__device__ __forceinline__ float fsigmoid(float x) { return 1.0f / (1.0f + __expf(-x)); }
__device__ __forceinline__ float ftanh(float x) {
  return 1.0f - 2.0f / (__expf(2.0f * x) + 1.0f);
}

__device__ __forceinline__ void gload16(const void* g, void* l) {
  __builtin_amdgcn_global_load_lds(
      (const __attribute__((address_space(1))) unsigned int*)(uintptr_t)g,
      (__attribute__((address_space(3))) unsigned int*)(uintptr_t)l, 16, 0, 0);
}

// ---------------- ws layout (round-2 proven 16KB panels, BK=64) ----------------
// A (inputs at 0, state at OFF_STATE): panel(rb,kb) = rb*32+kb, rb,kb in [0,32),
//   16KB each: [128 rows][64 k] bf16.
// W at OFF_W: w in {0:th_u,1:et_u,2:th_w,3:et_w,4:wx}; panel = w*512 + nb*32 + kb.
// Intra-panel byte(r,k) = r*128 + ((2k) ^ ((r&7)<<4))
#define WS_NEED   75497472ull
#define OFF_STATE (16ull << 20)
#define OFF_W     (32ull << 20)

// ---------- conversion: activations (identical to round 2) ----------
__global__ __launch_bounds__(256) void act_convert(
    const float* __restrict__ inputs, const float* __restrict__ state,
    char* __restrict__ dst) {
  unsigned gid = blockIdx.x * 256 + threadIdx.x;   // 2M chunks of 16B
  const float* src = inputs;
  char* d = dst;
  unsigned id = gid;
  if (gid >= (1u << 20)) { src = state; d = dst + OFF_STATE; id = gid - (1u << 20); }
  const unsigned cid = id & 1023, panel = id >> 10;
  const unsigned kb = panel & 31, rb = panel >> 5;
  const unsigned x = cid * 16, r = x >> 7, xb = x & 127;
  const unsigned k0 = (xb ^ ((r & 7) << 4)) >> 1;
  const float* s = src + (size_t)(rb * 128 + r) * KD + kb * 64 + k0;
  const float4 v0 = *reinterpret_cast<const float4*>(s);
  const float4 v1 = *reinterpret_cast<const float4*>(s + 4);
  uint4 w;
  w.x = (unsigned)f2bf(v0.x) | ((unsigned)f2bf(v0.y) << 16);
  w.y = (unsigned)f2bf(v0.z) | ((unsigned)f2bf(v0.w) << 16);
  w.z = (unsigned)f2bf(v1.x) | ((unsigned)f2bf(v1.y) << 16);
  w.w = (unsigned)f2bf(v1.z) | ((unsigned)f2bf(v1.w) << 16);
  *reinterpret_cast<uint4*>(d + (size_t)id * 16) = w;
}

// ---------- conversion: weights (identical to round 2) ----------
__global__ __launch_bounds__(256) void weight_convert(
    const float* __restrict__ tu, const float* __restrict__ eu,
    const float* __restrict__ tw, const float* __restrict__ ew,
    const float* __restrict__ xw, char* __restrict__ dst) {
  __shared__ float tile[64][129];
  const int tid = threadIdx.x;
  const int b = blockIdx.x;                 // 0..2559
  const int w = b >> 9, panel = b & 511;
  const int nb = panel >> 5, kb = panel & 31;
  const float* W = (w == 0) ? tu : (w == 1) ? eu : (w == 2) ? tw : (w == 3) ? ew : xw;
#pragma unroll
  for (int i = 0; i < 8; ++i) {
    const int idx = i * 256 + tid;
    const int row = idx >> 5, c4 = idx & 31;
    const float4 v = *reinterpret_cast<const float4*>(
        W + (size_t)(kb * 64 + row) * HD + nb * 128 + c4 * 4);
    tile[row][c4 * 4 + 0] = v.x; tile[row][c4 * 4 + 1] = v.y;
    tile[row][c4 * 4 + 2] = v.z; tile[row][c4 * 4 + 3] = v.w;
  }
  __syncthreads();
  char* d = dst + OFF_W + ((size_t)(w * 512 + panel) << 14);
#pragma unroll
  for (int i = 0; i < 4; ++i) {
    const int cid = i * 256 + tid;
    const int n = cid >> 3, xb = (cid & 7) * 16;
    const int k0 = (xb ^ ((n & 7) << 4)) >> 1;
    uint4 ww;
    ww.x = (unsigned)f2bf(tile[k0 + 0][n]) | ((unsigned)f2bf(tile[k0 + 1][n]) << 16);
    ww.y = (unsigned)f2bf(tile[k0 + 2][n]) | ((unsigned)f2bf(tile[k0 + 3][n]) << 16);
    ww.z = (unsigned)f2bf(tile[k0 + 4][n]) | ((unsigned)f2bf(tile[k0 + 5][n]) << 16);
    ww.w = (unsigned)f2bf(tile[k0 + 6][n]) | ((unsigned)f2bf(tile[k0 + 7][n]) << 16);
    *reinterpret_cast<uint4*>(d + n * 128 + xb) = ww;
  }
}

// ---------- fused main: BM=256 x BN=128, BK=64, 8 waves, dbuf + aged prefetch ----------
// Buffer (80KB): [A0 16K][A1 16K][B0 16K][B1 16K][B2 16K]; two buffers = 160KB.
__global__ __launch_bounds__(512, 2) void cfn_main(
    const char* __restrict__ ws, const float* __restrict__ state,
    const float* __restrict__ th_b, const float* __restrict__ et_b,
    float* __restrict__ out) {
  __shared__ char sm[163840];
  const int tid = threadIdx.x;
  int bid = blockIdx.x;
  bid = (bid & 7) * 32 + (bid >> 3);        // XCD swizzle (256 % 8 == 0)
  const int bx = bid & 15, by = bid >> 4;
  const int lane = tid & 63, wv = tid >> 6;
  const int wm = wv >> 2, wn = wv & 3;      // 2M x 4N waves -> per-wave 128x32
  const int lr = lane & 15, lg = lane >> 4;
  const int t16 = tid * 16;

  const char* pAx = ws;
  const char* pAs = ws + OFF_STATE;
  const char* pW  = ws + OFF_W;

  f32x4 at[8][2], ae[8][2], ax[8][2];
#pragma unroll
  for (int m = 0; m < 8; ++m)
#pragma unroll
    for (int n = 0; n < 2; ++n)
#pragma unroll
      for (int v = 0; v < 4; ++v) { at[m][n][v] = 0.f; ae[m][n][v] = 0.f; ax[m][n][v] = 0.f; }

  // A panels: rb = by*2 + p  -> panel index by*64 + p*32 + kb
  auto stageA = [&](int t, char* dst) {
    const int kb = t & 31;
    const char* pA = (t < 32) ? pAs : pAx;
#pragma unroll
    for (int p = 0; p < 2; ++p) {
      const char* pa = pA + ((size_t)(by * 64 + p * 32 + kb) << 14);
#pragma unroll
      for (int j = 0; j < 2; ++j)
        gload16(pa + t16 + j * 8192, dst + p * 16384 + t16 + j * 8192);
    }
  };
  auto stageB = [&](int t, char* dst) {
    const int kb = t & 31;
    const int w0 = (t < 32) ? 0 : 2;
    const int nB = (t < 32) ? 2 : 3;
#pragma unroll
    for (int q = 0; q < 3; ++q) {
      if (q < nB) {
        const char* pb = pW + ((size_t)((w0 + q) * 512 + bx * 32 + kb) << 14);
#pragma unroll
        for (int j = 0; j < 2; ++j)
          gload16(pb + t16 + j * 8192, dst + 32768 + q * 16384 + t16 + j * 8192);
      }
    }
  };

  // one kk-phase: read frags, MFMA cluster under setprio
  auto phase = [&](const char* buf, int PH, int nMat) {
    const int sw = (PH * 64 + lg * 16) ^ ((lr & 7) << 4);
    const char* pa = buf + wm * 16384 + lr * 128 + sw;
    bf16x8 a[8];
#pragma unroll
    for (int m = 0; m < 8; ++m)
      a[m] = *reinterpret_cast<const bf16x8*>(pa + m * 2048);
    const char* pb = buf + 32768 + (wn * 32 + lr) * 128 + sw;
    bf16x8 b[3][2];
#pragma unroll
    for (int q = 0; q < 3; ++q)
      if (q < nMat) {
        b[q][0] = *reinterpret_cast<const bf16x8*>(pb + q * 16384);
        b[q][1] = *reinterpret_cast<const bf16x8*>(pb + q * 16384 + 2048);
      }
    __builtin_amdgcn_s_setprio(1);
#pragma unroll
    for (int m = 0; m < 8; ++m)
#pragma unroll
      for (int n = 0; n < 2; ++n) {
        at[m][n] = __builtin_amdgcn_mfma_f32_16x16x32_bf16(a[m], b[0][n], at[m][n], 0, 0, 0);
        ae[m][n] = __builtin_amdgcn_mfma_f32_16x16x32_bf16(a[m], b[1][n], ae[m][n], 0, 0, 0);
        if (nMat == 3)
          ax[m][n] = __builtin_amdgcn_mfma_f32_16x16x32_bf16(a[m], b[2][n], ax[m][n], 0, 0, 0);
      }
    __builtin_amdgcn_s_setprio(0);
  };

  stageA(0, sm);
  stageB(0, sm);

  for (int t = 0; t < 64; ++t) {
    char* cur = sm + (size_t)(t & 1) * 81920;
    char* nxt = sm + (size_t)((t + 1) & 1) * 81920;
    // loads for tile t were issued a full kb ago -> this wait is cheap;
    // barrier makes every wave's staging globally visible before reads.
    asm volatile("s_waitcnt vmcnt(0)" ::: "memory");
    __builtin_amdgcn_s_barrier();
    const bool pre = (t < 63);
    if (pre) stageA(t + 1, nxt);             // A prefetch overlaps phase 0
    if (t < 32) phase(cur, 0, 2); else phase(cur, 0, 3);
    __builtin_amdgcn_s_barrier();            // keep waves phase-locked (no drain)
    if (pre) stageB(t + 1, nxt);             // B prefetch overlaps phase 1
    if (t < 32) phase(cur, 1, 2); else phase(cur, 1, 3);
  }

  // ---- epilogue (nontemporal stores) ----
  float* const out2 = out + (size_t)BATCH * HD;
  const int n0 = bx * 128 + wn * 32;
  const int m0 = by * 256 + wm * 128;
#pragma unroll
  for (int n = 0; n < 2; ++n) {
    const int c = n0 + n * 16 + lr;
    const float tb = th_b[c], eb = et_b[c];
#pragma unroll
    for (int m = 0; m < 8; ++m) {
#pragma unroll
      for (int v = 0; v < 4; ++v) {
        const int r = m0 + m * 16 + lg * 4 + v;
        const float st = state[(size_t)r * HD + c];
        const float h = fsigmoid(at[m][n][v] + tb) * ftanh(st)
                      + fsigmoid(ae[m][n][v] + eb) * ftanh(ax[m][n][v]);
        __builtin_nontemporal_store(h, &out[(size_t)r * HD + c]);
        __builtin_nontemporal_store(h, &out2[(size_t)r * HD + c]);
      }
    }
  }
}

// ---------------- fallback if ws too small ----------------
__global__ __launch_bounds__(256, 2) void cfn_fallback(
    const float* __restrict__ inputs, const float* __restrict__ state,
    const float* __restrict__ th_u, const float* __restrict__ th_w,
    const float* __restrict__ th_b, const float* __restrict__ et_u,
    const float* __restrict__ et_w, const float* __restrict__ et_b,
    const float* __restrict__ wx_w, float* __restrict__ out) {
  __shared__ unsigned short sA[128 * 64];
  __shared__ unsigned short sB[128 * 64];
  char* const sAb = (char*)sA;
  char* const sBb = (char*)sB;
  const int tid = threadIdx.x;
  const int n0 = blockIdx.x * 128;
  const int m0 = blockIdx.y * 128;
  const int lane = tid & 63, wv = tid >> 6;
  const int wr = wv >> 1, wc = wv & 1;
  const int lr = lane & 15, lg = lane >> 4;
  const int a_kq = tid & 15, a_mb = tid >> 4;
  const int b_n = tid & 127, b_k8 = (tid >> 7) * 8;
  f32x4 acc[4][4], r2[4][4];
  auto zero_acc = [&]() {
#pragma unroll
    for (int m = 0; m < 4; ++m)
#pragma unroll
      for (int n = 0; n < 4; ++n) {
        acc[m][n][0] = 0.f; acc[m][n][1] = 0.f; acc[m][n][2] = 0.f; acc[m][n][3] = 0.f;
      }
  };
  auto gemm_seg = [&](const float* __restrict__ Ap, const float* __restrict__ Wp) {
    for (int k0 = 0; k0 < KD; k0 += 64) {
#pragma unroll
      for (int p = 0; p < 8; ++p) {
        const int m = p * 16 + a_mb;
        const float4 v = *reinterpret_cast<const float4*>(
            Ap + (size_t)(m0 + m) * KD + k0 + a_kq * 4);
        uint2 w;
        w.x = (unsigned)f2bf(v.x) | ((unsigned)f2bf(v.y) << 16);
        w.y = (unsigned)f2bf(v.z) | ((unsigned)f2bf(v.w) << 16);
        const int byte = m * 128 + ((a_kq * 8) ^ ((m & 7) << 4));
        *reinterpret_cast<uint2*>(sAb + byte) = w;
      }
#pragma unroll
      for (int p = 0; p < 4; ++p) {
        const int kb = p * 16 + b_k8;
        const float* bp = Wp + (size_t)(k0 + kb) * HD + n0 + b_n;
        uint4 w;
        w.x = (unsigned)f2bf(bp[0 * HD]) | ((unsigned)f2bf(bp[1 * HD]) << 16);
        w.y = (unsigned)f2bf(bp[2 * HD]) | ((unsigned)f2bf(bp[3 * HD]) << 16);
        w.z = (unsigned)f2bf(bp[4 * HD]) | ((unsigned)f2bf(bp[5 * HD]) << 16);
        w.w = (unsigned)f2bf(bp[6 * HD]) | ((unsigned)f2bf(bp[7 * HD]) << 16);
        const int byte = b_n * 128 + ((kb * 2) ^ ((b_n & 7) << 4));
        *reinterpret_cast<uint4*>(sBb + byte) = w;
      }
      __syncthreads();
#pragma unroll
      for (int kk = 0; kk < 2; ++kk) {
        bf16x8 af[4], bfr[4];
#pragma unroll
        for (int m = 0; m < 4; ++m) {
          const int r = wr * 64 + m * 16 + lr;
          af[m] = *reinterpret_cast<const bf16x8*>(sAb + r * 128 + ((kk * 64 + lg * 16) ^ ((r & 7) << 4)));
        }
#pragma unroll
        for (int n = 0; n < 4; ++n) {
          const int c = wc * 64 + n * 16 + lr;
          bfr[n] = *reinterpret_cast<const bf16x8*>(sBb + c * 128 + ((kk * 64 + lg * 16) ^ ((c & 7) << 4)));
        }
#pragma unroll
        for (int m = 0; m < 4; ++m)
#pragma unroll
          for (int n = 0; n < 4; ++n)
            acc[m][n] = __builtin_amdgcn_mfma_f32_16x16x32_bf16(af[m], bfr[n], acc[m][n], 0, 0, 0);
      }
      __syncthreads();
    }
  };
  zero_acc();
  gemm_seg(state, et_u);
  gemm_seg(inputs, et_w);
#pragma unroll
  for (int n = 0; n < 4; ++n) {
    const int c = n0 + wc * 64 + n * 16 + lr;
    const float eb = et_b[c];
#pragma unroll
    for (int m = 0; m < 4; ++m)
#pragma unroll
      for (int v = 0; v < 4; ++v) r2[m][n][v] = fsigmoid(acc[m][n][v] + eb);
  }
  zero_acc();
  gemm_seg(inputs, wx_w);
#pragma unroll
  for (int m = 0; m < 4; ++m)
#pragma unroll
    for (int n = 0; n < 4; ++n)
#pragma unroll
      for (int v = 0; v < 4; ++v) r2[m][n][v] *= ftanh(acc[m][n][v]);
  zero_acc();
  gemm_seg(state, th_u);
  gemm_seg(inputs, th_w);
  float* const out2 = out + (size_t)BATCH * HD;
#pragma unroll
  for (int n = 0; n < 4; ++n) {
    const int c = n0 + wc * 64 + n * 16 + lr;
    const float tb = th_b[c];
#pragma unroll
    for (int m = 0; m < 4; ++m)
#pragma unroll
      for (int v = 0; v < 4; ++v) {
        const int r = m0 + wr * 64 + m * 16 + lg * 4 + v;
        const float st = state[(size_t)r * HD + c];
        const float h = fsigmoid(acc[m][n][v] + tb) * ftanh(st) + r2[m][n][v];
        out[(size_t)r * HD + c] = h;
        out2[(size_t)r * HD + c] = h;
      }
  }
}

extern "C" void kernel_launch(void* const* d_in, const int* in_sizes, int n_in,
                              void* d_out, int out_size, void* d_ws, size_t ws_size,
                              hipStream_t stream) {
  const float* inputs = (const float*)d_in[0];
  const float* state  = (const float*)d_in[1];
  const float* th_u   = (const float*)d_in[2];
  const float* th_w   = (const float*)d_in[3];
  const float* th_b   = (const float*)d_in[4];
  const float* et_u   = (const float*)d_in[5];
  const float* et_w   = (const float*)d_in[6];
  const float* et_b   = (const float*)d_in[7];
  const float* wx_w   = (const float*)d_in[8];
  float* out = (float*)d_out;

  if (ws_size < WS_NEED) {
    dim3 grid(HD / 128, BATCH / 128);
    hipLaunchKernelGGL(cfn_fallback, grid, dim3(256), 0, stream,
                       inputs, state, th_u, th_w, th_b, et_u, et_w, et_b, wx_w, out);
    return;
  }

  char* ws = (char*)d_ws;
  hipLaunchKernelGGL(act_convert, dim3(8192), dim3(256), 0, stream, inputs, state, ws);
  hipLaunchKernelGGL(weight_convert, dim3(2560), dim3(256), 0, stream,
                     th_u, et_u, th_w, et_w, wx_w, ws);
  hipLaunchKernelGGL(cfn_main, dim3(256), dim3(512), 0, stream,
                     ws, state, th_b, et_b, out);
}

// Round 6
// 1788.522 us; speedup vs baseline: 1.1796x; 1.1796x over previous
//
#include <hip/hip_runtime.h>
#include <hip/hip_bf16.h>

#define BATCH 4096
#define KD    2048
#define HD    2048

typedef float f32x4 __attribute__((ext_vector_type(4)));
typedef short bf16x8 __attribute__((ext_vector_type(8)));

__device__ __forceinline__ unsigned short f2bf(float f) {
  unsigned int u = __builtin_bit_cast(unsigned int, f);
  u = (u + 0x7fffu + ((u >> 16) & 1u)) >> 16;   // RNE (inputs bounded, no NaN)
  return (unsigned short)u;
}

__device__ __forceinline__ float fsigmoid(float x) { return 1.0f / (1.0f + __expf(-x)); }
__device__ __forceinline__ float ftanh(float x) {
  return 1.0f - 2.0f / (__expf(2.0f * x) + 1.0f);
}

__device__ __forceinline__ void gload16(const void* g, void* l) {
  __builtin_amdgcn_global_load_lds(
      (const __attribute__((address_space(1))) unsigned int*)(uintptr_t)g,
      (__attribute__((address_space(3))) unsigned int*)(uintptr_t)l, 16, 0, 0);
}

// ---------------- ws layout (round-2 proven 16KB panels, BK=64) ----------------
// A (inputs at 0, state at OFF_STATE): panel(rb,kb) = rb*32+kb, rb,kb in [0,32),
//   16KB each: [128 rows][64 k] bf16.
// W at OFF_W: w in {0:th_u,1:et_u,2:th_w,3:et_w,4:wx}; panel = w*512 + nb*32 + kb.
// Intra-panel byte(r,k) = r*128 + ((2k) ^ ((r&7)<<4))
#define WS_NEED   75497472ull
#define OFF_STATE (16ull << 20)
#define OFF_W     (32ull << 20)

// ---------- conversion: activations (identical to round 2) ----------
__global__ __launch_bounds__(256) void act_convert(
    const float* __restrict__ inputs, const float* __restrict__ state,
    char* __restrict__ dst) {
  unsigned gid = blockIdx.x * 256 + threadIdx.x;   // 2M chunks of 16B
  const float* src = inputs;
  char* d = dst;
  unsigned id = gid;
  if (gid >= (1u << 20)) { src = state; d = dst + OFF_STATE; id = gid - (1u << 20); }
  const unsigned cid = id & 1023, panel = id >> 10;
  const unsigned kb = panel & 31, rb = panel >> 5;
  const unsigned x = cid * 16, r = x >> 7, xb = x & 127;
  const unsigned k0 = (xb ^ ((r & 7) << 4)) >> 1;
  const float* s = src + (size_t)(rb * 128 + r) * KD + kb * 64 + k0;
  const float4 v0 = *reinterpret_cast<const float4*>(s);
  const float4 v1 = *reinterpret_cast<const float4*>(s + 4);
  uint4 w;
  w.x = (unsigned)f2bf(v0.x) | ((unsigned)f2bf(v0.y) << 16);
  w.y = (unsigned)f2bf(v0.z) | ((unsigned)f2bf(v0.w) << 16);
  w.z = (unsigned)f2bf(v1.x) | ((unsigned)f2bf(v1.y) << 16);
  w.w = (unsigned)f2bf(v1.z) | ((unsigned)f2bf(v1.w) << 16);
  *reinterpret_cast<uint4*>(d + (size_t)id * 16) = w;
}

// ---------- conversion: weights (identical to round 2) ----------
__global__ __launch_bounds__(256) void weight_convert(
    const float* __restrict__ tu, const float* __restrict__ eu,
    const float* __restrict__ tw, const float* __restrict__ ew,
    const float* __restrict__ xw, char* __restrict__ dst) {
  __shared__ float tile[64][129];
  const int tid = threadIdx.x;
  const int b = blockIdx.x;                 // 0..2559
  const int w = b >> 9, panel = b & 511;
  const int nb = panel >> 5, kb = panel & 31;
  const float* W = (w == 0) ? tu : (w == 1) ? eu : (w == 2) ? tw : (w == 3) ? ew : xw;
#pragma unroll
  for (int i = 0; i < 8; ++i) {
    const int idx = i * 256 + tid;
    const int row = idx >> 5, c4 = idx & 31;
    const float4 v = *reinterpret_cast<const float4*>(
        W + (size_t)(kb * 64 + row) * HD + nb * 128 + c4 * 4);
    tile[row][c4 * 4 + 0] = v.x; tile[row][c4 * 4 + 1] = v.y;
    tile[row][c4 * 4 + 2] = v.z; tile[row][c4 * 4 + 3] = v.w;
  }
  __syncthreads();
  char* d = dst + OFF_W + ((size_t)(w * 512 + panel) << 14);
#pragma unroll
  for (int i = 0; i < 4; ++i) {
    const int cid = i * 256 + tid;
    const int n = cid >> 3, xb = (cid & 7) * 16;
    const int k0 = (xb ^ ((n & 7) << 4)) >> 1;
    uint4 ww;
    ww.x = (unsigned)f2bf(tile[k0 + 0][n]) | ((unsigned)f2bf(tile[k0 + 1][n]) << 16);
    ww.y = (unsigned)f2bf(tile[k0 + 2][n]) | ((unsigned)f2bf(tile[k0 + 3][n]) << 16);
    ww.z = (unsigned)f2bf(tile[k0 + 4][n]) | ((unsigned)f2bf(tile[k0 + 5][n]) << 16);
    ww.w = (unsigned)f2bf(tile[k0 + 6][n]) | ((unsigned)f2bf(tile[k0 + 7][n]) << 16);
    *reinterpret_cast<uint4*>(d + n * 128 + xb) = ww;
  }
}

// ---------- fused main: BM=256 x BN=128, BK=64, 8 waves, aged dbuf prefetch ----------
// Buffer (80KB): [A0 16K][A1 16K][B0 16K][B1 16K][B2 16K]; two buffers = 160KB.
// Register discipline (round-5 lesson): acc 192 (AGPR) + b[3][2]=24 + ONE a frag
// reused per m. No batched a[8] — that spilled.
__global__ __launch_bounds__(512, 2) void cfn_main(
    const char* __restrict__ ws, const float* __restrict__ state,
    const float* __restrict__ th_b, const float* __restrict__ et_b,
    float* __restrict__ out) {
  __shared__ char sm[163840];
  const int tid = threadIdx.x;
  int bid = blockIdx.x;
  bid = (bid & 7) * 32 + (bid >> 3);        // XCD swizzle (256 % 8 == 0)
  const int bx = bid & 15, by = bid >> 4;
  const int lane = tid & 63, wv = tid >> 6;
  const int wm = wv >> 2, wn = wv & 3;      // 2M x 4N waves -> per-wave 128x32
  const int lr = lane & 15, lg = lane >> 4;
  const int t16 = tid * 16;

  const char* pAx = ws;
  const char* pAs = ws + OFF_STATE;
  const char* pW  = ws + OFF_W;

  f32x4 at[8][2], ae[8][2], ax[8][2];
#pragma unroll
  for (int m = 0; m < 8; ++m)
#pragma unroll
    for (int n = 0; n < 2; ++n)
#pragma unroll
      for (int v = 0; v < 4; ++v) { at[m][n][v] = 0.f; ae[m][n][v] = 0.f; ax[m][n][v] = 0.f; }

  auto stageA = [&](int t, char* dst) {
    const int kb = t & 31;
    const char* pA = (t < 32) ? pAs : pAx;
#pragma unroll
    for (int p = 0; p < 2; ++p) {
      const char* pa = pA + ((size_t)(by * 64 + p * 32 + kb) << 14);
#pragma unroll
      for (int j = 0; j < 2; ++j)
        gload16(pa + t16 + j * 8192, dst + p * 16384 + t16 + j * 8192);
    }
  };
  auto stageB = [&](int t, char* dst) {
    const int kb = t & 31;
    const int w0 = (t < 32) ? 0 : 2;
    const int nB = (t < 32) ? 2 : 3;
#pragma unroll
    for (int q = 0; q < 3; ++q) {
      if (q < nB) {
        const char* pb = pW + ((size_t)((w0 + q) * 512 + bx * 32 + kb) << 14);
#pragma unroll
        for (int j = 0; j < 2; ++j)
          gload16(pb + t16 + j * 8192, dst + 32768 + q * 16384 + t16 + j * 8192);
      }
    }
  };

  // one kk-phase, 2 B-matrices (pass 1): R3-style register-lean body
  auto phase2 = [&](const char* buf, int kk) {
    const int sw = (kk * 64 + lg * 16) ^ ((lr & 7) << 4);
    const char* pb = buf + 32768 + (wn * 32 + lr) * 128 + sw;
    bf16x8 b0[2], b1[2];
    b0[0] = *reinterpret_cast<const bf16x8*>(pb);
    b0[1] = *reinterpret_cast<const bf16x8*>(pb + 2048);
    b1[0] = *reinterpret_cast<const bf16x8*>(pb + 16384);
    b1[1] = *reinterpret_cast<const bf16x8*>(pb + 16384 + 2048);
    const char* pa = buf + wm * 16384 + lr * 128 + sw;
    __builtin_amdgcn_s_setprio(1);
#pragma unroll
    for (int m = 0; m < 8; ++m) {
      const bf16x8 a = *reinterpret_cast<const bf16x8*>(pa + m * 2048);
#pragma unroll
      for (int n = 0; n < 2; ++n) {
        at[m][n] = __builtin_amdgcn_mfma_f32_16x16x32_bf16(a, b0[n], at[m][n], 0, 0, 0);
        ae[m][n] = __builtin_amdgcn_mfma_f32_16x16x32_bf16(a, b1[n], ae[m][n], 0, 0, 0);
      }
    }
    __builtin_amdgcn_s_setprio(0);
  };
  // one kk-phase, 3 B-matrices (pass 2)
  auto phase3 = [&](const char* buf, int kk) {
    const int sw = (kk * 64 + lg * 16) ^ ((lr & 7) << 4);
    const char* pb = buf + 32768 + (wn * 32 + lr) * 128 + sw;
    bf16x8 b0[2], b1[2], b2[2];
    b0[0] = *reinterpret_cast<const bf16x8*>(pb);
    b0[1] = *reinterpret_cast<const bf16x8*>(pb + 2048);
    b1[0] = *reinterpret_cast<const bf16x8*>(pb + 16384);
    b1[1] = *reinterpret_cast<const bf16x8*>(pb + 16384 + 2048);
    b2[0] = *reinterpret_cast<const bf16x8*>(pb + 32768);
    b2[1] = *reinterpret_cast<const bf16x8*>(pb + 32768 + 2048);
    const char* pa = buf + wm * 16384 + lr * 128 + sw;
    __builtin_amdgcn_s_setprio(1);
#pragma unroll
    for (int m = 0; m < 8; ++m) {
      const bf16x8 a = *reinterpret_cast<const bf16x8*>(pa + m * 2048);
#pragma unroll
      for (int n = 0; n < 2; ++n) {
        at[m][n] = __builtin_amdgcn_mfma_f32_16x16x32_bf16(a, b0[n], at[m][n], 0, 0, 0);
        ae[m][n] = __builtin_amdgcn_mfma_f32_16x16x32_bf16(a, b1[n], ae[m][n], 0, 0, 0);
        ax[m][n] = __builtin_amdgcn_mfma_f32_16x16x32_bf16(a, b2[n], ax[m][n], 0, 0, 0);
      }
    }
    __builtin_amdgcn_s_setprio(0);
  };

  stageA(0, sm);
  stageB(0, sm);

  for (int t = 0; t < 64; ++t) {
    char* cur = sm + (size_t)(t & 1) * 81920;
    char* nxt = sm + (size_t)((t + 1) & 1) * 81920;
    // stage(t) was issued a full iteration ago -> cheap wait;
    // barrier makes all waves' staging visible before reads.
    asm volatile("s_waitcnt vmcnt(0)" ::: "memory");
    __builtin_amdgcn_s_barrier();
    const bool pre = (t < 63);
    if (pre) stageA(t + 1, nxt);             // A prefetch overlaps phase kk=0
    if (t < 32) phase2(cur, 0); else phase3(cur, 0);
    __builtin_amdgcn_s_barrier();            // phase-lock waves (no counter drain)
    if (pre) stageB(t + 1, nxt);             // B prefetch overlaps phase kk=1
    if (t < 32) phase2(cur, 1); else phase3(cur, 1);
  }

  // ---- epilogue ----
  float* const out2 = out + (size_t)BATCH * HD;
  const int n0 = bx * 128 + wn * 32;
  const int m0 = by * 256 + wm * 128;
#pragma unroll
  for (int n = 0; n < 2; ++n) {
    const int c = n0 + n * 16 + lr;
    const float tb = th_b[c], eb = et_b[c];
#pragma unroll
    for (int m = 0; m < 8; ++m) {
#pragma unroll
      for (int v = 0; v < 4; ++v) {
        const int r = m0 + m * 16 + lg * 4 + v;
        const float st = state[(size_t)r * HD + c];
        const float h = fsigmoid(at[m][n][v] + tb) * ftanh(st)
                      + fsigmoid(ae[m][n][v] + eb) * ftanh(ax[m][n][v]);
        out[(size_t)r * HD + c] = h;
        out2[(size_t)r * HD + c] = h;
      }
    }
  }
}

// ---------------- fallback if ws too small ----------------
__global__ __launch_bounds__(256, 2) void cfn_fallback(
    const float* __restrict__ inputs, const float* __restrict__ state,
    const float* __restrict__ th_u, const float* __restrict__ th_w,
    const float* __restrict__ th_b, const float* __restrict__ et_u,
    const float* __restrict__ et_w, const float* __restrict__ et_b,
    const float* __restrict__ wx_w, float* __restrict__ out) {
  __shared__ unsigned short sA[128 * 64];
  __shared__ unsigned short sB[128 * 64];
  char* const sAb = (char*)sA;
  char* const sBb = (char*)sB;
  const int tid = threadIdx.x;
  const int n0 = blockIdx.x * 128;
  const int m0 = blockIdx.y * 128;
  const int lane = tid & 63, wv = tid >> 6;
  const int wr = wv >> 1, wc = wv & 1;
  const int lr = lane & 15, lg = lane >> 4;
  const int a_kq = tid & 15, a_mb = tid >> 4;
  const int b_n = tid & 127, b_k8 = (tid >> 7) * 8;
  f32x4 acc[4][4], r2[4][4];
  auto zero_acc = [&]() {
#pragma unroll
    for (int m = 0; m < 4; ++m)
#pragma unroll
      for (int n = 0; n < 4; ++n) {
        acc[m][n][0] = 0.f; acc[m][n][1] = 0.f; acc[m][n][2] = 0.f; acc[m][n][3] = 0.f;
      }
  };
  auto gemm_seg = [&](const float* __restrict__ Ap, const float* __restrict__ Wp) {
    for (int k0 = 0; k0 < KD; k0 += 64) {
#pragma unroll
      for (int p = 0; p < 8; ++p) {
        const int m = p * 16 + a_mb;
        const float4 v = *reinterpret_cast<const float4*>(
            Ap + (size_t)(m0 + m) * KD + k0 + a_kq * 4);
        uint2 w;
        w.x = (unsigned)f2bf(v.x) | ((unsigned)f2bf(v.y) << 16);
        w.y = (unsigned)f2bf(v.z) | ((unsigned)f2bf(v.w) << 16);
        const int byte = m * 128 + ((a_kq * 8) ^ ((m & 7) << 4));
        *reinterpret_cast<uint2*>(sAb + byte) = w;
      }
#pragma unroll
      for (int p = 0; p < 4; ++p) {
        const int kb = p * 16 + b_k8;
        const float* bp = Wp + (size_t)(k0 + kb) * HD + n0 + b_n;
        uint4 w;
        w.x = (unsigned)f2bf(bp[0 * HD]) | ((unsigned)f2bf(bp[1 * HD]) << 16);
        w.y = (unsigned)f2bf(bp[2 * HD]) | ((unsigned)f2bf(bp[3 * HD]) << 16);
        w.z = (unsigned)f2bf(bp[4 * HD]) | ((unsigned)f2bf(bp[5 * HD]) << 16);
        w.w = (unsigned)f2bf(bp[6 * HD]) | ((unsigned)f2bf(bp[7 * HD]) << 16);
        const int byte = b_n * 128 + ((kb * 2) ^ ((b_n & 7) << 4));
        *reinterpret_cast<uint4*>(sBb + byte) = w;
      }
      __syncthreads();
#pragma unroll
      for (int kk = 0; kk < 2; ++kk) {
        bf16x8 af[4], bfr[4];
#pragma unroll
        for (int m = 0; m < 4; ++m) {
          const int r = wr * 64 + m * 16 + lr;
          af[m] = *reinterpret_cast<const bf16x8*>(sAb + r * 128 + ((kk * 64 + lg * 16) ^ ((r & 7) << 4)));
        }
#pragma unroll
        for (int n = 0; n < 4; ++n) {
          const int c = wc * 64 + n * 16 + lr;
          bfr[n] = *reinterpret_cast<const bf16x8*>(sBb + c * 128 + ((kk * 64 + lg * 16) ^ ((c & 7) << 4)));
        }
#pragma unroll
        for (int m = 0; m < 4; ++m)
#pragma unroll
          for (int n = 0; n < 4; ++n)
            acc[m][n] = __builtin_amdgcn_mfma_f32_16x16x32_bf16(af[m], bfr[n], acc[m][n], 0, 0, 0);
      }
      __syncthreads();
    }
  };
  zero_acc();
  gemm_seg(state, et_u);
  gemm_seg(inputs, et_w);
#pragma unroll
  for (int n = 0; n < 4; ++n) {
    const int c = n0 + wc * 64 + n * 16 + lr;
    const float eb = et_b[c];
#pragma unroll
    for (int m = 0; m < 4; ++m)
#pragma unroll
      for (int v = 0; v < 4; ++v) r2[m][n][v] = fsigmoid(acc[m][n][v] + eb);
  }
  zero_acc();
  gemm_seg(inputs, wx_w);
#pragma unroll
  for (int m = 0; m < 4; ++m)
#pragma unroll
    for (int n = 0; n < 4; ++n)
#pragma unroll
      for (int v = 0; v < 4; ++v) r2[m][n][v] *= ftanh(acc[m][n][v]);
  zero_acc();
  gemm_seg(state, th_u);
  gemm_seg(inputs, th_w);
  float* const out2 = out + (size_t)BATCH * HD;
#pragma unroll
  for (int n = 0; n < 4; ++n) {
    const int c = n0 + wc * 64 + n * 16 + lr;
    const float tb = th_b[c];
#pragma unroll
    for (int m = 0; m < 4; ++m)
#pragma unroll
      for (int v = 0; v < 4; ++v) {
        const int r = m0 + wr * 64 + m * 16 + lg * 4 + v;
        const float st = state[(size_t)r * HD + c];
        const float h = fsigmoid(acc[m][n][v] + tb) * ftanh(st) + r2[m][n][v];
        out[(size_t)r * HD + c] = h;
        out2[(size_t)r * HD + c] = h;
      }
  }
}

extern "C" void kernel_launch(void* const* d_in, const int* in_sizes, int n_in,
                              void* d_out, int out_size, void* d_ws, size_t ws_size,
                              hipStream_t stream) {
  const float* inputs = (const float*)d_in[0];
  const float* state  = (const float*)d_in[1];
  const float* th_u   = (const float*)d_in[2];
  const float* th_w   = (const float*)d_in[3];
  const float* th_b   = (const float*)d_in[4];
  const float* et_u   = (const float*)d_in[5];
  const float* et_w   = (const float*)d_in[6];
  const float* et_b   = (const float*)d_in[7];
  const float* wx_w   = (const float*)d_in[8];
  float* out = (float*)d_out;

  if (ws_size < WS_NEED) {
    dim3 grid(HD / 128, BATCH / 128);
    hipLaunchKernelGGL(cfn_fallback, grid, dim3(256), 0, stream,
                       inputs, state, th_u, th_w, th_b, et_u, et_w, et_b, wx_w, out);
    return;
  }

  char* ws = (char*)d_ws;
  hipLaunchKernelGGL(act_convert, dim3(8192), dim3(256), 0, stream, inputs, state, ws);
  hipLaunchKernelGGL(weight_convert, dim3(2560), dim3(256), 0, stream,
                     th_u, et_u, th_w, et_w, wx_w, ws);
  hipLaunchKernelGGL(cfn_main, dim3(256), dim3(512), 0, stream,
                     ws, state, th_b, et_b, out);
}

// Round 7
// 183.463 us; speedup vs baseline: 11.4995x; 9.7487x over previous
//
#include <hip/hip_runtime.h>
#include <hip/hip_bf16.h>

#define BATCH 4096
#define KD    2048
#define HD    2048

typedef float f32x4 __attribute__((ext_vector_type(4)));
typedef short bf16x8 __attribute__((ext_vector_type(8)));

__device__ __forceinline__ unsigned short f2bf(float f) {
  unsigned int u = __builtin_bit_cast(unsigned int, f);
  u = (u + 0x7fffu + ((u >> 16) & 1u)) >> 16;   // RNE (inputs bounded, no NaN)
  return (unsigned short)u;
}

__device__ __forceinline__ float fsigmoid(float x) { return 1.0f / (1.0f + __expf(-x)); }
__device__ __forceinline__ float ftanh(float x) {
  return 1.0f - 2.0f / (__expf(2.0f * x) + 1.0f);
}

__device__ __forceinline__ void gload16(const void* g, void* l) {
  __builtin_amdgcn_global_load_lds(
      (const __attribute__((address_space(1))) unsigned int*)(uintptr_t)g,
      (__attribute__((address_space(3))) unsigned int*)(uintptr_t)l, 16, 0, 0);
}

// ---------------- ws layout (round-2 proven 16KB panels, BK=64) ----------------
// A (inputs at 0, state at OFF_STATE): panel(rb,kb) = rb*32+kb, 16KB: [128 r][64 k].
// W at OFF_W: w in {0:th_u,1:et_u,2:th_w,3:et_w,4:wx}; panel = w*512 + nb*32 + kb.
// Intra-panel byte(r,k) = r*128 + ((2k) ^ ((r&7)<<4))
#define WS_NEED   75497472ull
#define OFF_STATE (16ull << 20)
#define OFF_W     (32ull << 20)

// ---------- conversion: activations (identical to round 2) ----------
__global__ __launch_bounds__(256) void act_convert(
    const float* __restrict__ inputs, const float* __restrict__ state,
    char* __restrict__ dst) {
  unsigned gid = blockIdx.x * 256 + threadIdx.x;   // 2M chunks of 16B
  const float* src = inputs;
  char* d = dst;
  unsigned id = gid;
  if (gid >= (1u << 20)) { src = state; d = dst + OFF_STATE; id = gid - (1u << 20); }
  const unsigned cid = id & 1023, panel = id >> 10;
  const unsigned kb = panel & 31, rb = panel >> 5;
  const unsigned x = cid * 16, r = x >> 7, xb = x & 127;
  const unsigned k0 = (xb ^ ((r & 7) << 4)) >> 1;
  const float* s = src + (size_t)(rb * 128 + r) * KD + kb * 64 + k0;
  const float4 v0 = *reinterpret_cast<const float4*>(s);
  const float4 v1 = *reinterpret_cast<const float4*>(s + 4);
  uint4 w;
  w.x = (unsigned)f2bf(v0.x) | ((unsigned)f2bf(v0.y) << 16);
  w.y = (unsigned)f2bf(v0.z) | ((unsigned)f2bf(v0.w) << 16);
  w.z = (unsigned)f2bf(v1.x) | ((unsigned)f2bf(v1.y) << 16);
  w.w = (unsigned)f2bf(v1.z) | ((unsigned)f2bf(v1.w) << 16);
  *reinterpret_cast<uint4*>(d + (size_t)id * 16) = w;
}

// ---------- conversion: weights (identical to round 2) ----------
__global__ __launch_bounds__(256) void weight_convert(
    const float* __restrict__ tu, const float* __restrict__ eu,
    const float* __restrict__ tw, const float* __restrict__ ew,
    const float* __restrict__ xw, char* __restrict__ dst) {
  __shared__ float tile[64][129];
  const int tid = threadIdx.x;
  const int b = blockIdx.x;                 // 0..2559
  const int w = b >> 9, panel = b & 511;
  const int nb = panel >> 5, kb = panel & 31;
  const float* W = (w == 0) ? tu : (w == 1) ? eu : (w == 2) ? tw : (w == 3) ? ew : xw;
#pragma unroll
  for (int i = 0; i < 8; ++i) {
    const int idx = i * 256 + tid;
    const int row = idx >> 5, c4 = idx & 31;
    const float4 v = *reinterpret_cast<const float4*>(
        W + (size_t)(kb * 64 + row) * HD + nb * 128 + c4 * 4);
    tile[row][c4 * 4 + 0] = v.x; tile[row][c4 * 4 + 1] = v.y;
    tile[row][c4 * 4 + 2] = v.z; tile[row][c4 * 4 + 3] = v.w;
  }
  __syncthreads();
  char* d = dst + OFF_W + ((size_t)(w * 512 + panel) << 14);
#pragma unroll
  for (int i = 0; i < 4; ++i) {
    const int cid = i * 256 + tid;
    const int n = cid >> 3, xb = (cid & 7) * 16;
    const int k0 = (xb ^ ((n & 7) << 4)) >> 1;
    uint4 ww;
    ww.x = (unsigned)f2bf(tile[k0 + 0][n]) | ((unsigned)f2bf(tile[k0 + 1][n]) << 16);
    ww.y = (unsigned)f2bf(tile[k0 + 2][n]) | ((unsigned)f2bf(tile[k0 + 3][n]) << 16);
    ww.z = (unsigned)f2bf(tile[k0 + 4][n]) | ((unsigned)f2bf(tile[k0 + 5][n]) << 16);
    ww.w = (unsigned)f2bf(tile[k0 + 6][n]) | ((unsigned)f2bf(tile[k0 + 7][n]) << 16);
    *reinterpret_cast<uint4*>(d + n * 128 + xb) = ww;
  }
}

// ---------- fused main kernel: round-2 structure, bx-per-XCD swizzle ----------
__global__ __launch_bounds__(256, 2) void cfn_main(
    const char* __restrict__ ws, const float* __restrict__ state,
    const float* __restrict__ th_b, const float* __restrict__ et_b,
    float* __restrict__ out) {
  __shared__ char sm[65536];
  const int tid = threadIdx.x;
  // XCD-locality swizzle: HW round-robins orig bid -> XCD (orig&7).
  // Give each XCD a fixed bx pair {2x,2x+1}: its B working set (2-3MB/pass)
  // becomes L2-resident; A panels shared by the bx pair (2x reuse).
  const int orig = blockIdx.x;
  const int xcd = orig & 7, idx = orig >> 3;     // 512 blocks: idx in [0,64)
  const int bx = xcd * 2 + (idx & 1);            // [0,16)
  const int by = idx >> 1;                       // [0,32)
  const int lane = tid & 63, wv = tid >> 6;
  const int wr = wv >> 1, wc = wv & 1;
  const int lr = lane & 15, lg = lane >> 4;
  const int t16 = tid * 16;

  const char* pAx = ws;
  const char* pAs = ws + OFF_STATE;
  const char* pW  = ws + OFF_W;

  f32x4 at[4][4], ae[4][4], ax[4][4];
#pragma unroll
  for (int m = 0; m < 4; ++m)
#pragma unroll
    for (int n = 0; n < 4; ++n)
#pragma unroll
      for (int v = 0; v < 4; ++v) { at[m][n][v] = 0.f; ae[m][n][v] = 0.f; ax[m][n][v] = 0.f; }

  // ---- pass 1: state @ th_u -> at ; state @ et_u -> ae ----
  for (int kb = 0; kb < 32; ++kb) {
    const char* ga = pAs + ((size_t)(by * 32 + kb) << 14);
    const char* g0 = pW + ((size_t)(0 * 512 + bx * 32 + kb) << 14);
    const char* g1 = pW + ((size_t)(1 * 512 + bx * 32 + kb) << 14);
#pragma unroll
    for (int i = 0; i < 4; ++i) {
      gload16(ga + t16 + i * 4096, sm + t16 + i * 4096);
      gload16(g0 + t16 + i * 4096, sm + 16384 + t16 + i * 4096);
      gload16(g1 + t16 + i * 4096, sm + 32768 + t16 + i * 4096);
    }
    __syncthreads();
#pragma unroll
    for (int kk = 0; kk < 2; ++kk) {
      const int kc = kk * 64 + lg * 16;
      bf16x8 a[4], b[4];
#pragma unroll
      for (int m = 0; m < 4; ++m) {
        const int r = wr * 64 + m * 16 + lr;
        a[m] = *reinterpret_cast<const bf16x8*>(sm + r * 128 + (kc ^ ((r & 7) << 4)));
      }
#pragma unroll
      for (int n = 0; n < 4; ++n) {
        const int c = wc * 64 + n * 16 + lr;
        b[n] = *reinterpret_cast<const bf16x8*>(sm + 16384 + c * 128 + (kc ^ ((c & 7) << 4)));
      }
#pragma unroll
      for (int m = 0; m < 4; ++m)
#pragma unroll
        for (int n = 0; n < 4; ++n)
          at[m][n] = __builtin_amdgcn_mfma_f32_16x16x32_bf16(a[m], b[n], at[m][n], 0, 0, 0);
#pragma unroll
      for (int n = 0; n < 4; ++n) {
        const int c = wc * 64 + n * 16 + lr;
        b[n] = *reinterpret_cast<const bf16x8*>(sm + 32768 + c * 128 + (kc ^ ((c & 7) << 4)));
      }
#pragma unroll
      for (int m = 0; m < 4; ++m)
#pragma unroll
        for (int n = 0; n < 4; ++n)
          ae[m][n] = __builtin_amdgcn_mfma_f32_16x16x32_bf16(a[m], b[n], ae[m][n], 0, 0, 0);
    }
    __syncthreads();
  }

  // ---- pass 2: inputs @ th_w -> at ; inputs @ et_w -> ae ; inputs @ wx -> ax ----
  for (int kb = 0; kb < 32; ++kb) {
    const char* ga = pAx + ((size_t)(by * 32 + kb) << 14);
    const char* g0 = pW + ((size_t)(2 * 512 + bx * 32 + kb) << 14);
    const char* g1 = pW + ((size_t)(3 * 512 + bx * 32 + kb) << 14);
    const char* g2 = pW + ((size_t)(4 * 512 + bx * 32 + kb) << 14);
#pragma unroll
    for (int i = 0; i < 4; ++i) {
      gload16(ga + t16 + i * 4096, sm + t16 + i * 4096);
      gload16(g0 + t16 + i * 4096, sm + 16384 + t16 + i * 4096);
      gload16(g1 + t16 + i * 4096, sm + 32768 + t16 + i * 4096);
      gload16(g2 + t16 + i * 4096, sm + 49152 + t16 + i * 4096);
    }
    __syncthreads();
#pragma unroll
    for (int kk = 0; kk < 2; ++kk) {
      const int kc = kk * 64 + lg * 16;
      bf16x8 a[4], b[4];
#pragma unroll
      for (int m = 0; m < 4; ++m) {
        const int r = wr * 64 + m * 16 + lr;
        a[m] = *reinterpret_cast<const bf16x8*>(sm + r * 128 + (kc ^ ((r & 7) << 4)));
      }
#pragma unroll
      for (int n = 0; n < 4; ++n) {
        const int c = wc * 64 + n * 16 + lr;
        b[n] = *reinterpret_cast<const bf16x8*>(sm + 16384 + c * 128 + (kc ^ ((c & 7) << 4)));
      }
#pragma unroll
      for (int m = 0; m < 4; ++m)
#pragma unroll
        for (int n = 0; n < 4; ++n)
          at[m][n] = __builtin_amdgcn_mfma_f32_16x16x32_bf16(a[m], b[n], at[m][n], 0, 0, 0);
#pragma unroll
      for (int n = 0; n < 4; ++n) {
        const int c = wc * 64 + n * 16 + lr;
        b[n] = *reinterpret_cast<const bf16x8*>(sm + 32768 + c * 128 + (kc ^ ((c & 7) << 4)));
      }
#pragma unroll
      for (int m = 0; m < 4; ++m)
#pragma unroll
        for (int n = 0; n < 4; ++n)
          ae[m][n] = __builtin_amdgcn_mfma_f32_16x16x32_bf16(a[m], b[n], ae[m][n], 0, 0, 0);
#pragma unroll
      for (int n = 0; n < 4; ++n) {
        const int c = wc * 64 + n * 16 + lr;
        b[n] = *reinterpret_cast<const bf16x8*>(sm + 49152 + c * 128 + (kc ^ ((c & 7) << 4)));
      }
#pragma unroll
      for (int m = 0; m < 4; ++m)
#pragma unroll
        for (int n = 0; n < 4; ++n)
          ax[m][n] = __builtin_amdgcn_mfma_f32_16x16x32_bf16(a[m], b[n], ax[m][n], 0, 0, 0);
    }
    __syncthreads();
  }

  // ---- epilogue (nontemporal output stores: keep L2/LLC clean for panels) ----
  float* const out2 = out + (size_t)BATCH * HD;
  const int n0 = bx * 128, m0 = by * 128;
#pragma unroll
  for (int n = 0; n < 4; ++n) {
    const int c = n0 + wc * 64 + n * 16 + lr;
    const float tb = th_b[c], eb = et_b[c];
#pragma unroll
    for (int m = 0; m < 4; ++m) {
#pragma unroll
      for (int v = 0; v < 4; ++v) {
        const int r = m0 + wr * 64 + m * 16 + lg * 4 + v;
        const float st = state[(size_t)r * HD + c];
        const float h = fsigmoid(at[m][n][v] + tb) * ftanh(st)
                      + fsigmoid(ae[m][n][v] + eb) * ftanh(ax[m][n][v]);
        __builtin_nontemporal_store(h, &out[(size_t)r * HD + c]);
        __builtin_nontemporal_store(h, &out2[(size_t)r * HD + c]);
      }
    }
  }
}

// ---------------- fallback if ws too small ----------------
__global__ __launch_bounds__(256, 2) void cfn_fallback(
    const float* __restrict__ inputs, const float* __restrict__ state,
    const float* __restrict__ th_u, const float* __restrict__ th_w,
    const float* __restrict__ th_b, const float* __restrict__ et_u,
    const float* __restrict__ et_w, const float* __restrict__ et_b,
    const float* __restrict__ wx_w, float* __restrict__ out) {
  __shared__ unsigned short sA[128 * 64];
  __shared__ unsigned short sB[128 * 64];
  char* const sAb = (char*)sA;
  char* const sBb = (char*)sB;
  const int tid = threadIdx.x;
  const int n0 = blockIdx.x * 128;
  const int m0 = blockIdx.y * 128;
  const int lane = tid & 63, wv = tid >> 6;
  const int wr = wv >> 1, wc = wv & 1;
  const int lr = lane & 15, lg = lane >> 4;
  const int a_kq = tid & 15, a_mb = tid >> 4;
  const int b_n = tid & 127, b_k8 = (tid >> 7) * 8;
  f32x4 acc[4][4], r2[4][4];
  auto zero_acc = [&]() {
#pragma unroll
    for (int m = 0; m < 4; ++m)
#pragma unroll
      for (int n = 0; n < 4; ++n) {
        acc[m][n][0] = 0.f; acc[m][n][1] = 0.f; acc[m][n][2] = 0.f; acc[m][n][3] = 0.f;
      }
  };
  auto gemm_seg = [&](const float* __restrict__ Ap, const float* __restrict__ Wp) {
    for (int k0 = 0; k0 < KD; k0 += 64) {
#pragma unroll
      for (int p = 0; p < 8; ++p) {
        const int m = p * 16 + a_mb;
        const float4 v = *reinterpret_cast<const float4*>(
            Ap + (size_t)(m0 + m) * KD + k0 + a_kq * 4);
        uint2 w;
        w.x = (unsigned)f2bf(v.x) | ((unsigned)f2bf(v.y) << 16);
        w.y = (unsigned)f2bf(v.z) | ((unsigned)f2bf(v.w) << 16);
        const int byte = m * 128 + ((a_kq * 8) ^ ((m & 7) << 4));
        *reinterpret_cast<uint2*>(sAb + byte) = w;
      }
#pragma unroll
      for (int p = 0; p < 4; ++p) {
        const int kb = p * 16 + b_k8;
        const float* bp = Wp + (size_t)(k0 + kb) * HD + n0 + b_n;
        uint4 w;
        w.x = (unsigned)f2bf(bp[0 * HD]) | ((unsigned)f2bf(bp[1 * HD]) << 16);
        w.y = (unsigned)f2bf(bp[2 * HD]) | ((unsigned)f2bf(bp[3 * HD]) << 16);
        w.z = (unsigned)f2bf(bp[4 * HD]) | ((unsigned)f2bf(bp[5 * HD]) << 16);
        w.w = (unsigned)f2bf(bp[6 * HD]) | ((unsigned)f2bf(bp[7 * HD]) << 16);
        const int byte = b_n * 128 + ((kb * 2) ^ ((b_n & 7) << 4));
        *reinterpret_cast<uint4*>(sBb + byte) = w;
      }
      __syncthreads();
#pragma unroll
      for (int kk = 0; kk < 2; ++kk) {
        bf16x8 af[4], bfr[4];
#pragma unroll
        for (int m = 0; m < 4; ++m) {
          const int r = wr * 64 + m * 16 + lr;
          af[m] = *reinterpret_cast<const bf16x8*>(sAb + r * 128 + ((kk * 64 + lg * 16) ^ ((r & 7) << 4)));
        }
#pragma unroll
        for (int n = 0; n < 4; ++n) {
          const int c = wc * 64 + n * 16 + lr;
          bfr[n] = *reinterpret_cast<const bf16x8*>(sBb + c * 128 + ((kk * 64 + lg * 16) ^ ((c & 7) << 4)));
        }
#pragma unroll
        for (int m = 0; m < 4; ++m)
#pragma unroll
          for (int n = 0; n < 4; ++n)
            acc[m][n] = __builtin_amdgcn_mfma_f32_16x16x32_bf16(af[m], bfr[n], acc[m][n], 0, 0, 0);
      }
      __syncthreads();
    }
  };
  zero_acc();
  gemm_seg(state, et_u);
  gemm_seg(inputs, et_w);
#pragma unroll
  for (int n = 0; n < 4; ++n) {
    const int c = n0 + wc * 64 + n * 16 + lr;
    const float eb = et_b[c];
#pragma unroll
    for (int m = 0; m < 4; ++m)
#pragma unroll
      for (int v = 0; v < 4; ++v) r2[m][n][v] = fsigmoid(acc[m][n][v] + eb);
  }
  zero_acc();
  gemm_seg(inputs, wx_w);
#pragma unroll
  for (int m = 0; m < 4; ++m)
#pragma unroll
    for (int n = 0; n < 4; ++n)
#pragma unroll
      for (int v = 0; v < 4; ++v) r2[m][n][v] *= ftanh(acc[m][n][v]);
  zero_acc();
  gemm_seg(state, th_u);
  gemm_seg(inputs, th_w);
  float* const out2 = out + (size_t)BATCH * HD;
#pragma unroll
  for (int n = 0; n < 4; ++n) {
    const int c = n0 + wc * 64 + n * 16 + lr;
    const float tb = th_b[c];
#pragma unroll
    for (int m = 0; m < 4; ++m)
#pragma unroll
      for (int v = 0; v < 4; ++v) {
        const int r = m0 + wr * 64 + m * 16 + lg * 4 + v;
        const float st = state[(size_t)r * HD + c];
        const float h = fsigmoid(acc[m][n][v] + tb) * ftanh(st) + r2[m][n][v];
        out[(size_t)r * HD + c] = h;
        out2[(size_t)r * HD + c] = h;
      }
  }
}

extern "C" void kernel_launch(void* const* d_in, const int* in_sizes, int n_in,
                              void* d_out, int out_size, void* d_ws, size_t ws_size,
                              hipStream_t stream) {
  const float* inputs = (const float*)d_in[0];
  const float* state  = (const float*)d_in[1];
  const float* th_u   = (const float*)d_in[2];
  const float* th_w   = (const float*)d_in[3];
  const float* th_b   = (const float*)d_in[4];
  const float* et_u   = (const float*)d_in[5];
  const float* et_w   = (const float*)d_in[6];
  const float* et_b   = (const float*)d_in[7];
  const float* wx_w   = (const float*)d_in[8];
  float* out = (float*)d_out;

  if (ws_size < WS_NEED) {
    dim3 grid(HD / 128, BATCH / 128);
    hipLaunchKernelGGL(cfn_fallback, grid, dim3(256), 0, stream,
                       inputs, state, th_u, th_w, th_b, et_u, et_w, et_b, wx_w, out);
    return;
  }

  char* ws = (char*)d_ws;
  hipLaunchKernelGGL(act_convert, dim3(8192), dim3(256), 0, stream, inputs, state, ws);
  hipLaunchKernelGGL(weight_convert, dim3(2560), dim3(256), 0, stream,
                     th_u, et_u, th_w, et_w, wx_w, ws);
  hipLaunchKernelGGL(cfn_main, dim3(512), dim3(256), 0, stream,
                     ws, state, th_b, et_b, out);
}